// Round 5
// baseline (549.496 us; speedup 1.0000x reference)
//
#include <hip/hip_runtime.h>

typedef unsigned short u16;
typedef unsigned int u32;
typedef __attribute__((ext_vector_type(8))) short bf16x8;
typedef __attribute__((ext_vector_type(16))) float f32x16;

#define CDIM 256
#define NDIM 16384
#define NBATCH 8
#define NCHUNK 32
#define CHUNK_N 512
#define TLEN 64
#define NTILES 8

// ws layout (bytes)
#define WS_WK  0u          // Wk bf16 [256][256]
#define WS_WV  131072u     // Wv bf16 [256][256]
#define WS_CTX 262144u     // ctx fp32 [8][256][256]
#define WS_L   2359296u    // l fp32 [8][256]
#define WS_END 2367488u

// Round-nearest-even f32 -> bf16 via bit manipulation (proven in round 1; no inline asm).
__device__ __forceinline__ u16 f2bf(float f) {
  union { float f; unsigned u; } v; v.f = f;
  return (u16)((v.u + 0x7fffu + ((v.u >> 16) & 1u)) >> 16);
}
// Two bf16 packed in a u32: low half = lo (element 0), high half = hi (element 1).
__device__ __forceinline__ u32 pack2(float lo, float hi) {
  return (u32)f2bf(lo) | ((u32)f2bf(hi) << 16);
}
// XOR-fold byte bits 7-9 into bank-quad bits 4-6; same formula on write & read.
// Only touches bits >=4, so 8B/16B-aligned slots map to aligned slots.
__device__ __forceinline__ int swz(int off) { return off ^ (((off >> 7) & 7) << 4); }

__global__ void prep_weights(const float* __restrict__ Wk, const float* __restrict__ Wv,
                             u16* __restrict__ wkb, u16* __restrict__ wvb) {
  int i = blockIdx.x * 256 + threadIdx.x;
  wkb[i] = f2bf(Wk[i]);
  wvb[i] = f2bf(Wv[i]);
}

// Pack one 32x64 D-strip (g0: D-cols' rows 0..31, g1: rows 32..63) into a swizzled
// [row][64] bf16 LDS tile: LDS-row = D-col (lane&31 + base), LDS-n = D-row
// m = (r&3)+8*(r>>2)+4*h  (m74/m101-verified 32x32 C/D layout).
__device__ __forceinline__ void pack_store(const f32x16& g0, const f32x16& g1,
                                           char* base, int row, int h) {
  #pragma unroll
  for (int nt = 0; nt < 2; ++nt) {
    const f32x16& g = nt ? g1 : g0;
    #pragma unroll
    for (int bq = 0; bq < 4; ++bq) {
      uint2 w;
      w.x = pack2(g[4 * bq + 0], g[4 * bq + 1]);
      w.y = pack2(g[4 * bq + 2], g[4 * bq + 3]);
      const int n = nt * 32 + 8 * bq + 4 * h;
      *reinterpret_cast<uint2*>(base + swz(row * 128 + n * 2)) = w;
    }
  }
}

__global__ __launch_bounds__(512) void attn_main(
    const float* __restrict__ x, const u16* __restrict__ wkb, const u16* __restrict__ wvb,
    float* __restrict__ ctx_acc, float* __restrict__ l_acc) {
  // 96 KB total static LDS
  __shared__ u16 xs[16384];      // x tile, c-octet-blocked [oct=c>>3][n][c&7], swizzled, 32 KB
  __shared__ u16 ps[16384];      // P tile [k][n] bf16, swizzled, 32 KB
  __shared__ u16 vs[16384];      // V^T tile [v][n] bf16, swizzled, 32 KB

  const int bid = blockIdx.x;
  const int chunk = bid & (NCHUNK - 1);
  const int b = bid >> 5;
  const int tid = threadIdx.x;
  const int wv = tid >> 6;        // wave 0..7: owns k rows wv*32..wv*32+31, reads all v rows
  const int lane = tid & 63;
  const int l31 = lane & 31;
  const int h = lane >> 5;

  const float* xb = x + (size_t)b * CDIM * NDIM + chunk * CHUNK_N;

  // staging mapping: thread owns one c-octet (8 consecutive c), 4 consecutive n
  const int so = tid >> 4;              // 0..31
  const int sc = so * 8;
  const int sn = (tid & 15) * 4;

  const u16* wkp = wkb + (wv * 32 + l31) * 256 + h * 8;
  const u16* wvp = wvb + (wv * 32 + l31) * 256 + h * 8;

  f32x16 acc[8] = {};   // ctx accumulator: own 32 k x 256 v
  float lsum = 0.f;

  char* xsb = (char*)&xs[0];
  char* psb = (char*)&ps[0];
  char* vsb = (char*)&vs[0];

  float4 pf[8];

  // ---- prologue: issue loads for tile 0 ----
  #pragma unroll
  for (int p = 0; p < 8; ++p)
    pf[p] = *reinterpret_cast<const float4*>(xb + (size_t)(sc + p) * NDIM + sn);

  for (int t = 0; t < NTILES; ++t) {
    // ---- stage x tile -> LDS from prefetch regs (bit-manip bf16 pack) ----
    {
      uint4 w0, w1, w2, w3;
      w0.x = pack2(pf[0].x, pf[1].x); w0.y = pack2(pf[2].x, pf[3].x); w0.z = pack2(pf[4].x, pf[5].x); w0.w = pack2(pf[6].x, pf[7].x);
      w1.x = pack2(pf[0].y, pf[1].y); w1.y = pack2(pf[2].y, pf[3].y); w1.z = pack2(pf[4].y, pf[5].y); w1.w = pack2(pf[6].y, pf[7].y);
      w2.x = pack2(pf[0].z, pf[1].z); w2.y = pack2(pf[2].z, pf[3].z); w2.z = pack2(pf[4].z, pf[5].z); w2.w = pack2(pf[6].z, pf[7].z);
      w3.x = pack2(pf[0].w, pf[1].w); w3.y = pack2(pf[2].w, pf[3].w); w3.z = pack2(pf[4].w, pf[5].w); w3.w = pack2(pf[6].w, pf[7].w);
      *reinterpret_cast<uint4*>(xsb + swz(so * 1024 + (sn + 0) * 16)) = w0;
      *reinterpret_cast<uint4*>(xsb + swz(so * 1024 + (sn + 1) * 16)) = w1;
      *reinterpret_cast<uint4*>(xsb + swz(so * 1024 + (sn + 2) * 16)) = w2;
      *reinterpret_cast<uint4*>(xsb + swz(so * 1024 + (sn + 3) * 16)) = w3;
    }
    __syncthreads();   // bar1: xs ready; prev tile's ctx readers done with ps/vs

    // ---- issue global loads for tile t+1 (hide under S/V/ctx compute) ----
    if (t < NTILES - 1) {
      #pragma unroll
      for (int p = 0; p < 8; ++p)
        pf[p] = *reinterpret_cast<const float4*>(xb + (size_t)(sc + p) * NDIM + (t + 1) * TLEN + sn);
    }

    // ---- S^T = X^T * Wk^T : D[n][k], k-cols = wv*32 + l31 ----
    f32x16 g0 = {}, g1 = {};
    #pragma unroll
    for (int kk = 0; kk < 16; ++kk) {
      const int oct = kk * 2 + h;
      bf16x8 a0 = *reinterpret_cast<const bf16x8*>(xsb + swz(oct * 1024 + l31 * 16));
      bf16x8 a1 = *reinterpret_cast<const bf16x8*>(xsb + swz(oct * 1024 + (32 + l31) * 16));
      bf16x8 bk = *reinterpret_cast<const bf16x8*>(wkp + kk * 16);
      g0 = __builtin_amdgcn_mfma_f32_32x32x16_bf16(a0, bk, g0, 0, 0, 0);
      g1 = __builtin_amdgcn_mfma_f32_32x32x16_bf16(a1, bk, g1, 0, 0, 0);
    }

    // ---- P = exp(S): denominator partials + pack to ps (LDS) ----
    float ls = 0.f;
    #pragma unroll
    for (int r = 0; r < 16; ++r) { g0[r] = __expf(g0[r]); ls += g0[r]; }
    #pragma unroll
    for (int r = 0; r < 16; ++r) { g1[r] = __expf(g1[r]); ls += g1[r]; }
    lsum += ls;
    pack_store(g0, g1, psb, wv * 32 + l31, h);

    // ---- V^T = X^T * Wv^T : D[n][v], pack to vs (LDS) ----
    g0 = {}; g1 = {};
    #pragma unroll
    for (int kk = 0; kk < 16; ++kk) {
      const int oct = kk * 2 + h;
      bf16x8 a0 = *reinterpret_cast<const bf16x8*>(xsb + swz(oct * 1024 + l31 * 16));
      bf16x8 a1 = *reinterpret_cast<const bf16x8*>(xsb + swz(oct * 1024 + (32 + l31) * 16));
      bf16x8 bw = *reinterpret_cast<const bf16x8*>(wvp + kk * 16);
      g0 = __builtin_amdgcn_mfma_f32_32x32x16_bf16(a0, bw, g0, 0, 0, 0);
      g1 = __builtin_amdgcn_mfma_f32_32x32x16_bf16(a1, bw, g1, 0, 0, 0);
    }
    pack_store(g0, g1, vsb, wv * 32 + l31, h);

    __syncthreads();   // bar2: ps + vs ready; all xs reads of this tile done

    // ---- ctx += P * V^T : own 32 k x 256 v ----
    bf16x8 paf[4];
    #pragma unroll
    for (int kk = 0; kk < 4; ++kk)
      paf[kk] = *reinterpret_cast<const bf16x8*>(
          psb + swz((wv * 32 + l31) * 128 + (kk * 16 + h * 8) * 2));
    #pragma unroll
    for (int vt = 0; vt < 8; ++vt) {
      #pragma unroll
      for (int kk = 0; kk < 4; ++kk) {
        bf16x8 bvf = *reinterpret_cast<const bf16x8*>(
            vsb + swz((vt * 32 + l31) * 128 + (kk * 16 + h * 8) * 2));
        acc[vt] = __builtin_amdgcn_mfma_f32_32x32x16_bf16(paf[kk], bvf, acc[vt], 0, 0, 0);
      }
    }
    // next iteration's bar1 separates these ctx reads from the next pack_store
  }

  // ---- epilogue ----
  lsum += __shfl_xor(lsum, 32);
  if (h == 0) atomicAdd(&l_acc[b * 256 + wv * 32 + l31], lsum);

  float* ctxb = ctx_acc + (size_t)b * 65536;
  #pragma unroll
  for (int vt = 0; vt < 8; ++vt) {
    #pragma unroll
    for (int r = 0; r < 16; ++r) {
      const int k = wv * 32 + (r & 3) + 8 * (r >> 2) + 4 * h;
      atomicAdd(&ctxb[k * 256 + vt * 32 + l31], acc[vt][r]);
    }
  }
}

__global__ void finalize_kernel(const float* __restrict__ ctx_acc, const float* __restrict__ l_acc,
                                const float* __restrict__ bv, float* __restrict__ out) {
  int idx = blockIdx.x * 256 + threadIdx.x;
  out[idx] = ctx_acc[idx] / l_acc[idx >> 8] + bv[idx & 255];
}

extern "C" void kernel_launch(void* const* d_in, const int* in_sizes, int n_in,
                              void* d_out, int out_size, void* d_ws, size_t ws_size,
                              hipStream_t stream) {
  const float* x  = (const float*)d_in[0];
  const float* Wk = (const float*)d_in[1];
  // d_in[2] = bk: constant over softmax axis -> cancels exactly, unused
  const float* Wv = (const float*)d_in[3];
  const float* bv = (const float*)d_in[4];
  float* out = (float*)d_out;
  char* ws = (char*)d_ws;

  u16* wkb = (u16*)(ws + WS_WK);
  u16* wvb = (u16*)(ws + WS_WV);
  float* ctx = (float*)(ws + WS_CTX);
  float* l   = (float*)(ws + WS_L);

  hipMemsetAsync(ws + WS_CTX, 0, WS_END - WS_CTX, stream);
  prep_weights<<<256, 256, 0, stream>>>(Wk, Wv, wkb, wvb);
  attn_main<<<NBATCH * NCHUNK, 512, 0, stream>>>(x, wkb, wvb, ctx, l);
  finalize_kernel<<<2048, 256, 0, stream>>>(ctx, l, bv, out);
}

// Round 6
// 515.023 us; speedup vs baseline: 1.0669x; 1.0669x over previous
//
#include <hip/hip_runtime.h>

typedef unsigned short u16;
typedef unsigned int u32;
typedef __attribute__((ext_vector_type(8))) short bf16x8;
typedef __attribute__((ext_vector_type(16))) float f32x16;

#define CDIM 256
#define NDIM 16384
#define NBATCH 8
#define NCHUNK 32
#define CHUNK_N 512
#define TLEN 64
#define NTILES 8

// ws layout (bytes)
#define WS_WK   0u          // Wk bf16 [256][256]
#define WS_WV   131072u     // Wv bf16 [256][256]
// direct mode (ws >= WS_NEED):
#define WS_PC   262144u     // partial ctx fp32 [256 blocks][256][256] = 64 MB
#define WS_LP   67371008u   // partial l fp32 [256 blocks][256] = 256 KB
#define WS_NEED 67633152u
// atomic fallback mode (round-5 proven):
#define WS_CTX  262144u     // ctx fp32 [8][256][256]
#define WS_L    2359296u    // l fp32 [8][256]
#define WS_AEND 2367488u

// Round-nearest-even f32 -> bf16 via bit manipulation (no inline asm).
__device__ __forceinline__ u16 f2bf(float f) {
  union { float f; unsigned u; } v; v.f = f;
  return (u16)((v.u + 0x7fffu + ((v.u >> 16) & 1u)) >> 16);
}
// Two bf16 packed in a u32: low half = lo (element 0), high half = hi (element 1).
__device__ __forceinline__ u32 pack2(float lo, float hi) {
  return (u32)f2bf(lo) | ((u32)f2bf(hi) << 16);
}
// XOR-fold byte bits 7-9 into bank-quad bits 4-6; same formula on write & read.
// Only touches bits >=4, so 8B/16B-aligned slots map to aligned slots.
__device__ __forceinline__ int swz(int off) { return off ^ (((off >> 7) & 7) << 4); }

__global__ void prep_weights(const float* __restrict__ Wk, const float* __restrict__ Wv,
                             u16* __restrict__ wkb, u16* __restrict__ wvb) {
  int i = blockIdx.x * 256 + threadIdx.x;
  wkb[i] = f2bf(Wk[i]);
  wvb[i] = f2bf(Wv[i]);
}

// Pack one 32x64 D-strip (g0: rows 0..31, g1: rows 32..63 of n) into a swizzled
// [row][64] bf16 LDS tile: LDS-row = D-col (lane&31 + base), LDS-n = D-row
// m = (r&3)+8*(r>>2)+4*h  (m74/m101-verified 32x32 C/D layout).
__device__ __forceinline__ void pack_store(const f32x16& g0, const f32x16& g1,
                                           char* base, int row, int h) {
  #pragma unroll
  for (int nt = 0; nt < 2; ++nt) {
    const f32x16& g = nt ? g1 : g0;
    #pragma unroll
    for (int bq = 0; bq < 4; ++bq) {
      uint2 w;
      w.x = pack2(g[4 * bq + 0], g[4 * bq + 1]);
      w.y = pack2(g[4 * bq + 2], g[4 * bq + 3]);
      const int n = nt * 32 + 8 * bq + 4 * h;
      *reinterpret_cast<uint2*>(base + swz(row * 128 + n * 2)) = w;
    }
  }
}

__global__ __launch_bounds__(512) void attn_main(
    const float* __restrict__ x, const u16* __restrict__ wkb, const u16* __restrict__ wvb,
    float* __restrict__ pc, float* __restrict__ lp,
    float* __restrict__ ctx_acc, float* __restrict__ l_acc, int direct) {
  // 96 KB total static LDS
  __shared__ u16 xs[16384];      // x tile, c-octet-blocked [oct=c>>3][n][c&7], swizzled, 32 KB
  __shared__ u16 ps[16384];      // P tile [k][n] bf16, swizzled, 32 KB
  __shared__ u16 vs[16384];      // V^T tile [v][n] bf16, swizzled, 32 KB

  const int bid = blockIdx.x;
  const int chunk = bid & (NCHUNK - 1);
  const int b = bid >> 5;
  const int tid = threadIdx.x;
  const int wv = tid >> 6;        // wave 0..7: owns k rows wv*32..wv*32+31, reads all v rows
  const int lane = tid & 63;
  const int l31 = lane & 31;
  const int h = lane >> 5;

  const float* xb = x + (size_t)b * CDIM * NDIM + chunk * CHUNK_N;

  // staging mapping: thread owns one c-octet (8 consecutive c), 4 consecutive n
  const int so = tid >> 4;              // 0..31
  const int sc = so * 8;
  const int sn = (tid & 15) * 4;

  const u16* wkp = wkb + (wv * 32 + l31) * 256 + h * 8;
  const u16* wvp = wvb + (wv * 32 + l31) * 256 + h * 8;

  f32x16 acc[8] = {};   // ctx accumulator: own 32 k x 256 v
  float lsum = 0.f;

  char* xsb = (char*)&xs[0];
  char* psb = (char*)&ps[0];
  char* vsb = (char*)&vs[0];

  float4 pf[8];

  // ---- prologue: issue loads for tile 0 ----
  #pragma unroll
  for (int p = 0; p < 8; ++p)
    pf[p] = *reinterpret_cast<const float4*>(xb + (size_t)(sc + p) * NDIM + sn);

  for (int t = 0; t < NTILES; ++t) {
    // ---- stage x tile -> LDS from prefetch regs (bit-manip bf16 pack) ----
    {
      uint4 w0, w1, w2, w3;
      w0.x = pack2(pf[0].x, pf[1].x); w0.y = pack2(pf[2].x, pf[3].x); w0.z = pack2(pf[4].x, pf[5].x); w0.w = pack2(pf[6].x, pf[7].x);
      w1.x = pack2(pf[0].y, pf[1].y); w1.y = pack2(pf[2].y, pf[3].y); w1.z = pack2(pf[4].y, pf[5].y); w1.w = pack2(pf[6].y, pf[7].y);
      w2.x = pack2(pf[0].z, pf[1].z); w2.y = pack2(pf[2].z, pf[3].z); w2.z = pack2(pf[4].z, pf[5].z); w2.w = pack2(pf[6].z, pf[7].z);
      w3.x = pack2(pf[0].w, pf[1].w); w3.y = pack2(pf[2].w, pf[3].w); w3.z = pack2(pf[4].w, pf[5].w); w3.w = pack2(pf[6].w, pf[7].w);
      *reinterpret_cast<uint4*>(xsb + swz(so * 1024 + (sn + 0) * 16)) = w0;
      *reinterpret_cast<uint4*>(xsb + swz(so * 1024 + (sn + 1) * 16)) = w1;
      *reinterpret_cast<uint4*>(xsb + swz(so * 1024 + (sn + 2) * 16)) = w2;
      *reinterpret_cast<uint4*>(xsb + swz(so * 1024 + (sn + 3) * 16)) = w3;
    }
    __syncthreads();   // bar1: xs ready; prev tile's ctx readers done with ps/vs

    // ---- issue global loads for tile t+1 (hide under S/V/ctx compute) ----
    if (t < NTILES - 1) {
      #pragma unroll
      for (int p = 0; p < 8; ++p)
        pf[p] = *reinterpret_cast<const float4*>(xb + (size_t)(sc + p) * NDIM + (t + 1) * TLEN + sn);
    }

    // ---- S^T = X^T * Wk^T : D[n][k], k-cols = wv*32 + l31 ----
    f32x16 g0 = {}, g1 = {};
    #pragma unroll
    for (int kk = 0; kk < 16; ++kk) {
      const int oct = kk * 2 + h;
      bf16x8 a0 = *reinterpret_cast<const bf16x8*>(xsb + swz(oct * 1024 + l31 * 16));
      bf16x8 a1 = *reinterpret_cast<const bf16x8*>(xsb + swz(oct * 1024 + (32 + l31) * 16));
      bf16x8 bk = *reinterpret_cast<const bf16x8*>(wkp + kk * 16);
      g0 = __builtin_amdgcn_mfma_f32_32x32x16_bf16(a0, bk, g0, 0, 0, 0);
      g1 = __builtin_amdgcn_mfma_f32_32x32x16_bf16(a1, bk, g1, 0, 0, 0);
    }

    // ---- P = exp(S): denominator partials + pack to ps (LDS) ----
    float ls = 0.f;
    #pragma unroll
    for (int r = 0; r < 16; ++r) { g0[r] = __expf(g0[r]); ls += g0[r]; }
    #pragma unroll
    for (int r = 0; r < 16; ++r) { g1[r] = __expf(g1[r]); ls += g1[r]; }
    lsum += ls;
    pack_store(g0, g1, psb, wv * 32 + l31, h);

    // ---- V^T = X^T * Wv^T : D[n][v], pack to vs (LDS) ----
    g0 = {}; g1 = {};
    #pragma unroll
    for (int kk = 0; kk < 16; ++kk) {
      const int oct = kk * 2 + h;
      bf16x8 a0 = *reinterpret_cast<const bf16x8*>(xsb + swz(oct * 1024 + l31 * 16));
      bf16x8 a1 = *reinterpret_cast<const bf16x8*>(xsb + swz(oct * 1024 + (32 + l31) * 16));
      bf16x8 bw = *reinterpret_cast<const bf16x8*>(wvp + kk * 16);
      g0 = __builtin_amdgcn_mfma_f32_32x32x16_bf16(a0, bw, g0, 0, 0, 0);
      g1 = __builtin_amdgcn_mfma_f32_32x32x16_bf16(a1, bw, g1, 0, 0, 0);
    }
    pack_store(g0, g1, vsb, wv * 32 + l31, h);

    __syncthreads();   // bar2: ps + vs ready; all xs reads of this tile done

    // ---- ctx += P * V^T : own 32 k x 256 v ----
    bf16x8 paf[4];
    #pragma unroll
    for (int kk = 0; kk < 4; ++kk)
      paf[kk] = *reinterpret_cast<const bf16x8*>(
          psb + swz((wv * 32 + l31) * 128 + (kk * 16 + h * 8) * 2));
    #pragma unroll
    for (int vt = 0; vt < 8; ++vt) {
      #pragma unroll
      for (int kk = 0; kk < 4; ++kk) {
        bf16x8 bvf = *reinterpret_cast<const bf16x8*>(
            vsb + swz((vt * 32 + l31) * 128 + (kk * 16 + h * 8) * 2));
        acc[vt] = __builtin_amdgcn_mfma_f32_32x32x16_bf16(paf[kk], bvf, acc[vt], 0, 0, 0);
      }
    }
    // next iteration's bar1 separates these ctx reads from the next pack_store
  }

  // ---- epilogue ----
  lsum += __shfl_xor(lsum, 32);

  if (direct) {
    // private per-block partial: plain coalesced stores, no atomics, no zero-init
    float* pcb = pc + (size_t)bid * 65536;
    #pragma unroll
    for (int vt = 0; vt < 8; ++vt) {
      #pragma unroll
      for (int r = 0; r < 16; ++r) {
        const int k = wv * 32 + (r & 3) + 8 * (r >> 2) + 4 * h;
        pcb[k * 256 + vt * 32 + l31] = acc[vt][r];
      }
    }
    if (h == 0) lp[bid * 256 + wv * 32 + l31] = lsum;
  } else {
    if (h == 0) atomicAdd(&l_acc[b * 256 + wv * 32 + l31], lsum);
    float* ctxb = ctx_acc + (size_t)b * 65536;
    #pragma unroll
    for (int vt = 0; vt < 8; ++vt) {
      #pragma unroll
      for (int r = 0; r < 16; ++r) {
        const int k = wv * 32 + (r & 3) + 8 * (r >> 2) + 4 * h;
        atomicAdd(&ctxb[k * 256 + vt * 32 + l31], acc[vt][r]);
      }
    }
  }
}

// direct mode: reduce 32 chunk-partials per batch, normalize, add bv.
// gid -> 4 consecutive v: v4 = gid*4; b = gid>>14, k = (gid>>6)&255, v = (gid&63)*4.
__global__ void finalize_direct(const float* __restrict__ pc, const float* __restrict__ lp,
                                const float* __restrict__ bv, float* __restrict__ out) {
  const int gid = blockIdx.x * 256 + threadIdx.x;   // 131072 threads
  const int b = gid >> 14;
  const int k = (gid >> 6) & 255;
  const int v = (gid & 63) * 4;
  float4 s = make_float4(0.f, 0.f, 0.f, 0.f);
  float lt = 0.f;
  #pragma unroll 8
  for (int c = 0; c < NCHUNK; ++c) {
    const int pb = b * NCHUNK + c;
    const float4 p4 = *reinterpret_cast<const float4*>(pc + (size_t)pb * 65536 + k * 256 + v);
    s.x += p4.x; s.y += p4.y; s.z += p4.z; s.w += p4.w;
    lt += lp[pb * 256 + k];
  }
  const float inv = 1.f / lt;
  const float4 b4 = *reinterpret_cast<const float4*>(bv + v);
  float4 o;
  o.x = s.x * inv + b4.x; o.y = s.y * inv + b4.y;
  o.z = s.z * inv + b4.z; o.w = s.w * inv + b4.w;
  *reinterpret_cast<float4*>(out + ((size_t)b << 16) + k * 256 + v) = o;
}

__global__ void finalize_atomic(const float* __restrict__ ctx_acc, const float* __restrict__ l_acc,
                                const float* __restrict__ bv, float* __restrict__ out) {
  int idx = blockIdx.x * 256 + threadIdx.x;
  out[idx] = ctx_acc[idx] / l_acc[idx >> 8] + bv[idx & 255];
}

extern "C" void kernel_launch(void* const* d_in, const int* in_sizes, int n_in,
                              void* d_out, int out_size, void* d_ws, size_t ws_size,
                              hipStream_t stream) {
  const float* x  = (const float*)d_in[0];
  const float* Wk = (const float*)d_in[1];
  // d_in[2] = bk: constant over softmax axis -> cancels exactly, unused
  const float* Wv = (const float*)d_in[3];
  const float* bv = (const float*)d_in[4];
  float* out = (float*)d_out;
  char* ws = (char*)d_ws;

  u16* wkb = (u16*)(ws + WS_WK);
  u16* wvb = (u16*)(ws + WS_WV);
  const int direct = (ws_size >= (size_t)WS_NEED) ? 1 : 0;

  float* pc  = (float*)(ws + WS_PC);
  float* lpp = (float*)(ws + WS_LP);
  float* ctx = (float*)(ws + WS_CTX);
  float* l   = (float*)(ws + WS_L);

  if (!direct) {
    // atomic fallback needs zeroed accumulators (ws is poisoned before every launch)
    hipMemsetAsync(ws + WS_CTX, 0, WS_AEND - WS_CTX, stream);
  }
  prep_weights<<<256, 256, 0, stream>>>(Wk, Wv, wkb, wvb);
  attn_main<<<NBATCH * NCHUNK, 512, 0, stream>>>(x, wkb, wvb, pc, lpp, ctx, l, direct);
  if (direct)
    finalize_direct<<<512, 256, 0, stream>>>(pc, lpp, bv, out);
  else
    finalize_atomic<<<2048, 256, 0, stream>>>(ctx, l, bv, out);
}